// Round 1
// baseline (46.448 us; speedup 1.0000x reference)
//
#include <hip/hip_runtime.h>
#include <math.h>

// Problem constants (V=4 views, N=8192 points, 6 unordered pairs)
#define VNUM   4
#define NPAIRS 6
#define BLK    256   // threads per block (4 waves)
#define APT    4     // a-points per thread
#define ATILE  (BLK * APT)  // 1024 a-points per block
#define BTILE  512          // b-points staged in LDS per block

// Kernel 1: transform points to world space, store float4(x,y,z,|p|^2);
// init per-(pair,a-point) min buffer to +FLT_MAX; zero the output scalar.
__global__ void setup_kernel(const float* __restrict__ points,
                             const float* __restrict__ poses,
                             float4* __restrict__ world,
                             unsigned int* __restrict__ minbuf,
                             float* __restrict__ out, int N) {
    int idx = blockIdx.x * blockDim.x + threadIdx.x;
    int total = NPAIRS * N;                    // 49152 (covers V*N = 32768 too)
    if (idx < total) minbuf[idx] = 0x7F7FFFFFu; // FLT_MAX bit pattern
    if (idx == 0) *out = 0.0f;
    int vn = VNUM * N;
    if (idx < vn) {
        int v = idx / N;
        const float* P = poses + v * 16;       // row-major 4x4
        float px = points[idx * 3 + 0];
        float py = points[idx * 3 + 1];
        float pz = points[idx * 3 + 2];
        float x = P[0] * px + P[1] * py + P[2]  * pz + P[3];
        float y = P[4] * px + P[5] * py + P[6]  * pz + P[7];
        float z = P[8] * px + P[9] * py + P[10] * pz + P[11];
        float s = x * x + y * y + z * z;
        world[idx] = make_float4(x, y, z, s);
    }
}

// Kernel 2: for pair p = (i,j), each thread owns 4 a-points (registers),
// block loops a 512-point b-tile from LDS. Track min over (|b|^2 - 2 a.b);
// add |a|^2 and clamp at the end, then atomicMin into the per-a-point slot.
__global__ __launch_bounds__(BLK)
void chamfer_kernel(const float4* __restrict__ world,
                    unsigned int* __restrict__ minbuf, int N) {
    __shared__ float4 sb[BTILE];
    const int bc = blockIdx.x;   // b-chunk
    const int ac = blockIdx.y;   // a-chunk
    const int p  = blockIdx.z;   // pair index
    const int pi = (p < 3) ? 0 : ((p < 5) ? 1 : 2);
    const int pj = (p < 3) ? (p + 1) : ((p < 5) ? (p - 1) : 3);
    const int tid = threadIdx.x;

    const float4* __restrict__ wa = world + pi * N + ac * ATILE;
    const float4* __restrict__ wb = world + pj * N + bc * BTILE;

    float ax[APT], ay[APT], az[APT], asq[APT], m[APT];
#pragma unroll
    for (int k = 0; k < APT; ++k) {
        float4 a = wa[tid + k * BLK];
        ax[k] = a.x; ay[k] = a.y; az[k] = a.z; asq[k] = a.w;
        m[k] = 3.402823466e38f;
    }

    // Stage b-tile with the -2 factor pre-applied: (-2x, -2y, -2z, |b|^2)
    for (int k = tid; k < BTILE; k += BLK) {
        float4 b = wb[k];
        sb[k] = make_float4(-2.0f * b.x, -2.0f * b.y, -2.0f * b.z, b.w);
    }
    __syncthreads();

#pragma unroll 4
    for (int kk = 0; kk < BTILE; ++kk) {
        float4 b = sb[kk];   // uniform address -> LDS broadcast, no conflicts
#pragma unroll
        for (int k = 0; k < APT; ++k) {
            float t = fmaf(ax[k], b.x, b.w);
            t = fmaf(ay[k], b.y, t);
            t = fmaf(az[k], b.z, t);
            m[k] = fminf(m[k], t);
        }
    }

#pragma unroll
    for (int k = 0; k < APT; ++k) {
        float v = fmaxf(m[k] + asq[k], 0.0f);   // non-negative -> uint order == float order
        atomicMin(&minbuf[p * N + ac * ATILE + tid + k * BLK],
                  __float_as_uint(v));
    }
}

// Kernel 3: d = sqrt(min d^2), block-reduce, scaled atomicAdd into scalar out.
__global__ void finalize_kernel(const unsigned int* __restrict__ minbuf,
                                float* __restrict__ out, float scale) {
    __shared__ float red[BLK / 64];
    int idx = blockIdx.x * blockDim.x + threadIdx.x;
    float d = sqrtf(__uint_as_float(minbuf[idx]));
#pragma unroll
    for (int off = 32; off >= 1; off >>= 1)
        d += __shfl_down(d, off, 64);
    int lane = threadIdx.x & 63;
    int wid  = threadIdx.x >> 6;
    if (lane == 0) red[wid] = d;
    __syncthreads();
    if (threadIdx.x == 0) {
        float s = 0.0f;
#pragma unroll
        for (int w = 0; w < BLK / 64; ++w) s += red[w];
        atomicAdd(out, s * scale);
    }
}

extern "C" void kernel_launch(void* const* d_in, const int* in_sizes, int n_in,
                              void* d_out, int out_size, void* d_ws, size_t ws_size,
                              hipStream_t stream) {
    const float* points = (const float*)d_in[0];   // V x N x 3 fp32
    const float* poses  = (const float*)d_in[1];   // V x 4 x 4 fp32
    float* out = (float*)d_out;                    // scalar fp32

    const int N = in_sizes[0] / (VNUM * 3);        // 8192

    // Workspace layout: world float4[V*N] (512 KB) | minbuf uint[6*N] (192 KB)
    float4* world = (float4*)d_ws;
    unsigned int* minbuf =
        (unsigned int*)((char*)d_ws + (size_t)VNUM * N * sizeof(float4));

    int setup_threads = NPAIRS * N;                // covers init + transform
    setup_kernel<<<(setup_threads + BLK - 1) / BLK, BLK, 0, stream>>>(
        points, poses, world, minbuf, out, N);

    dim3 grid(N / BTILE, N / ATILE, NPAIRS);       // 16 x 8 x 6 = 768 blocks
    chamfer_kernel<<<grid, BLK, 0, stream>>>(world, minbuf, N);

    finalize_kernel<<<(NPAIRS * N) / BLK, BLK, 0, stream>>>(
        minbuf, out, 1.0f / (6.0f * (float)N));
}

// Round 2
// 44.243 us; speedup vs baseline: 1.0498x; 1.0498x over previous
//
#include <hip/hip_runtime.h>
#include <math.h>

// Problem constants (V=4 views, N=8192 points, 6 unordered pairs)
#define VNUM   4
#define NPAIRS 6
#define BLK    256   // threads per block (4 waves)
#define APT    8     // a-points per thread
#define ATILE  (BLK * APT)  // 2048 a-points per block
#define BTILE  256          // b-points staged in LDS per block

// Kernel 1: transform points to world space, store float4(x,y,z,|p|^2);
// init per-(pair,a-point) min buffer to +FLT_MAX; zero the output scalar.
__global__ void setup_kernel(const float* __restrict__ points,
                             const float* __restrict__ poses,
                             float4* __restrict__ world,
                             unsigned int* __restrict__ minbuf,
                             float* __restrict__ out, int N) {
    int idx = blockIdx.x * blockDim.x + threadIdx.x;
    int total = NPAIRS * N;                    // 49152 (covers V*N = 32768 too)
    if (idx < total) minbuf[idx] = 0x7F7FFFFFu; // FLT_MAX bit pattern
    if (idx == 0) *out = 0.0f;
    int vn = VNUM * N;
    if (idx < vn) {
        int v = idx / N;
        const float* P = poses + v * 16;       // row-major 4x4
        float px = points[idx * 3 + 0];
        float py = points[idx * 3 + 1];
        float pz = points[idx * 3 + 2];
        float x = P[0] * px + P[1] * py + P[2]  * pz + P[3];
        float y = P[4] * px + P[5] * py + P[6]  * pz + P[7];
        float z = P[8] * px + P[9] * py + P[10] * pz + P[11];
        float s = x * x + y * y + z * z;
        world[idx] = make_float4(x, y, z, s);
    }
}

// Kernel 2: pair p=(i,j); each thread owns 8 a-points (registers); block
// loops a 256-point b-tile in LDS two b-points at a time. Track
// min over (|b|^2 - 2 a.b) via v_min3; add |a|^2 + clamp at the end,
// then atomicMin (float-as-uint, values >= 0) into the per-a-point slot.
__global__ __launch_bounds__(BLK)
void chamfer_kernel(const float4* __restrict__ world,
                    unsigned int* __restrict__ minbuf, int N) {
    __shared__ float4 sb[BTILE];
    const int bc = blockIdx.x;   // b-chunk
    const int ac = blockIdx.y;   // a-chunk
    const int p  = blockIdx.z;   // pair index
    const int pi = (p < 3) ? 0 : ((p < 5) ? 1 : 2);
    const int pj = (p < 3) ? (p + 1) : ((p < 5) ? (p - 1) : 3);
    const int tid = threadIdx.x;

    const float4* __restrict__ wa = world + pi * N + ac * ATILE;
    const float4* __restrict__ wb = world + pj * N + bc * BTILE;

    float ax[APT], ay[APT], az[APT], asq[APT], m[APT];
#pragma unroll
    for (int k = 0; k < APT; ++k) {
        float4 a = wa[tid + k * BLK];
        ax[k] = a.x; ay[k] = a.y; az[k] = a.z; asq[k] = a.w;
        m[k] = 3.402823466e38f;
    }

    // Stage b-tile with the -2 factor pre-applied: (-2x, -2y, -2z, |b|^2)
    {
        float4 b = wb[tid];      // BTILE == BLK: one float4 per thread
        sb[tid] = make_float4(-2.0f * b.x, -2.0f * b.y, -2.0f * b.z, b.w);
    }
    __syncthreads();

#pragma unroll 2
    for (int kk = 0; kk < BTILE; kk += 2) {
        float4 b0 = sb[kk];      // uniform address -> LDS broadcast
        float4 b1 = sb[kk + 1];
#pragma unroll
        for (int k = 0; k < APT; ++k) {
            float t0 = fmaf(ax[k], b0.x, b0.w);
            t0 = fmaf(ay[k], b0.y, t0);
            t0 = fmaf(az[k], b0.z, t0);
            float t1 = fmaf(ax[k], b1.x, b1.w);
            t1 = fmaf(ay[k], b1.y, t1);
            t1 = fmaf(az[k], b1.z, t1);
            // m = min(m, t0, t1) in one issue slot
            asm("v_min3_f32 %0, %1, %2, %0" : "+v"(m[k]) : "v"(t0), "v"(t1));
        }
    }

#pragma unroll
    for (int k = 0; k < APT; ++k) {
        float v = fmaxf(m[k] + asq[k], 0.0f);   // >=0 -> uint order == float order
        atomicMin(&minbuf[p * N + ac * ATILE + tid + k * BLK],
                  __float_as_uint(v));
    }
}

// Kernel 3: d = sqrt(min d^2), block-reduce, scaled atomicAdd into scalar out.
__global__ void finalize_kernel(const unsigned int* __restrict__ minbuf,
                                float* __restrict__ out, float scale) {
    __shared__ float red[BLK / 64];
    int idx = blockIdx.x * blockDim.x + threadIdx.x;
    float d = sqrtf(__uint_as_float(minbuf[idx]));
#pragma unroll
    for (int off = 32; off >= 1; off >>= 1)
        d += __shfl_down(d, off, 64);
    int lane = threadIdx.x & 63;
    int wid  = threadIdx.x >> 6;
    if (lane == 0) red[wid] = d;
    __syncthreads();
    if (threadIdx.x == 0) {
        float s = 0.0f;
#pragma unroll
        for (int w = 0; w < BLK / 64; ++w) s += red[w];
        atomicAdd(out, s * scale);
    }
}

extern "C" void kernel_launch(void* const* d_in, const int* in_sizes, int n_in,
                              void* d_out, int out_size, void* d_ws, size_t ws_size,
                              hipStream_t stream) {
    const float* points = (const float*)d_in[0];   // V x N x 3 fp32
    const float* poses  = (const float*)d_in[1];   // V x 4 x 4 fp32
    float* out = (float*)d_out;                    // scalar fp32

    const int N = in_sizes[0] / (VNUM * 3);        // 8192

    // Workspace layout: world float4[V*N] (512 KB) | minbuf uint[6*N] (192 KB)
    float4* world = (float4*)d_ws;
    unsigned int* minbuf =
        (unsigned int*)((char*)d_ws + (size_t)VNUM * N * sizeof(float4));

    int setup_threads = NPAIRS * N;                // covers init + transform
    setup_kernel<<<(setup_threads + BLK - 1) / BLK, BLK, 0, stream>>>(
        points, poses, world, minbuf, out, N);

    dim3 grid(N / BTILE, N / ATILE, NPAIRS);       // 32 x 4 x 6 = 768 blocks
    chamfer_kernel<<<grid, BLK, 0, stream>>>(world, minbuf, N);

    finalize_kernel<<<(NPAIRS * N) / BLK, BLK, 0, stream>>>(
        minbuf, out, 1.0f / (6.0f * (float)N));
}

// Round 5
// 34.454 us; speedup vs baseline: 1.3481x; 1.2841x over previous
//
#include <hip/hip_runtime.h>
#include <math.h>

// V=4 views, N=8192 points, 6 directed chamfer terms (pair p rows=view pi, min over view pj)
#define VNUM   4
#define NPAIRS 6
#define BLK    256

using short8  = __attribute__((ext_vector_type(8)))  short;
using f32x16  = __attribute__((ext_vector_type(16))) float;

__device__ inline unsigned short f2bf(float x) {           // RNE to bf16
    unsigned u = __float_as_uint(x);
    return (unsigned short)((u + 0x7FFFu + ((u >> 16) & 1u)) >> 16);
}
__device__ inline float bf2f(unsigned short b) {
    return __uint_as_float(((unsigned)b) << 16);
}

// Kernel 1: world-transform, build K=16 bf16 fragments so that
// dot(Afrag[a], Bfrag[b]) = |a|^2 + |b|^2 - 2*(a_hi+a_lo).(b_hi+b_lo).
__global__ void setup_kernel(const float* __restrict__ pts,
                             const float* __restrict__ poses,
                             unsigned short* __restrict__ afr,
                             unsigned short* __restrict__ bfr,
                             unsigned int* __restrict__ minbuf,
                             float* __restrict__ out, int N) {
    int idx = blockIdx.x * blockDim.x + threadIdx.x;
    if (idx < NPAIRS * N) minbuf[idx] = 0x7F7FFFFFu;       // FLT_MAX bits
    if (idx == 0) *out = 0.0f;
    if (idx < VNUM * N) {
        int v = idx / N;
        const float* P = poses + v * 16;                   // row-major 4x4
        float px = pts[idx*3+0], py = pts[idx*3+1], pz = pts[idx*3+2];
        float x = fmaf(P[0], px, fmaf(P[1], py, fmaf(P[2],  pz, P[3])));
        float y = fmaf(P[4], px, fmaf(P[5], py, fmaf(P[6],  pz, P[7])));
        float z = fmaf(P[8], px, fmaf(P[9], py, fmaf(P[10], pz, P[11])));
        float s = fmaf(x, x, fmaf(y, y, z * z));
        unsigned short xh = f2bf(x), yh = f2bf(y), zh = f2bf(z);
        unsigned short xl = f2bf(x - bf2f(xh));
        unsigned short yl = f2bf(y - bf2f(yh));
        unsigned short zl = f2bf(z - bf2f(zh));
        unsigned short sh = f2bf(s), sl = f2bf(s - bf2f(sh));
        const unsigned short one = 0x3F80u;
        // -2 * bf16 is exact (power-of-two scale)
        unsigned short bxh = f2bf(-2.0f * bf2f(xh)), byh = f2bf(-2.0f * bf2f(yh)),
                       bzh = f2bf(-2.0f * bf2f(zh));
        unsigned short bxl = f2bf(-2.0f * bf2f(xl)), byl = f2bf(-2.0f * bf2f(yl)),
                       bzl = f2bf(-2.0f * bf2f(zl));
        unsigned short* A = afr + (size_t)idx * 16;
        A[0]=xh;  A[1]=yh;  A[2]=zh;   A[3]=xh;  A[4]=yh;  A[5]=zh;
        A[6]=xl;  A[7]=yl;  A[8]=zl;   A[9]=sh;  A[10]=sl; A[11]=one; A[12]=one;
        A[13]=xl; A[14]=yl; A[15]=zl;
        unsigned short* B = bfr + (size_t)idx * 16;
        B[0]=bxh; B[1]=byh; B[2]=bzh;  B[3]=bxl; B[4]=byl; B[5]=bzl;
        B[6]=bxh; B[7]=byh; B[8]=bzh;  B[9]=one; B[10]=one; B[11]=sh; B[12]=sl;
        B[13]=bxl; B[14]=byl; B[15]=bzl;
    }
}

// Kernel 2: wave-task = (pair, 64 a-rows, 2048-b quarter). One 32x32x16 MFMA
// per (a-tile, b-tile); min-accumulate with plain fminf (NO inline asm on
// MFMA outputs -> backend hazard recognizer fully owns MFMA->VALU waits).
// C/D placement self-calibrated with a probe MFMA (D[m][n]=16m).
__global__ __launch_bounds__(BLK, 3)
void chamfer_kernel(const unsigned short* __restrict__ afr,
                    const unsigned short* __restrict__ bfr,
                    unsigned int* __restrict__ minbuf, int N) {
    const int p  = blockIdx.z;
    const int pi = (p < 3) ? 0 : ((p < 5) ? 1 : 2);
    const int pj = (p < 3) ? (p + 1) : ((p < 5) ? (p - 1) : 3);
    const int w    = threadIdx.x >> 6;
    const int l    = threadIdx.x & 63;
    const int col  = l & 31;
    const int half = l >> 5;

    const int abase = (blockIdx.y * 4 + w) * 64;  // 64 a-rows per wave
    const int b0    = blockIdx.x * 2048;          // b-quarter

    const short8* aptr =
        (const short8*)(afr + ((size_t)pi * N + abase + col) * 16 + half * 8);
    const short8 A0 = aptr[0];
    const short8 A1 = aptr[64];                   // +32 points
    const short8* bptr =
        (const short8*)(bfr + ((size_t)pj * N + b0 + col) * 16 + half * 8);

    f32x16 m0, m1, zz;
#pragma unroll
    for (int i = 0; i < 16; ++i) { m0[i] = 3.402823466e38f; m1[i] = 3.402823466e38f; zz[i] = 0.0f; }

    for (int t = 0; t < 64; t += 2) {             // 2 b-tiles per iteration
        short8 B0 = bptr[t * 64];
        short8 B1 = bptr[t * 64 + 64];
        f32x16 d00 = __builtin_amdgcn_mfma_f32_32x32x16_bf16(A0, B0, zz, 0, 0, 0);
        f32x16 d01 = __builtin_amdgcn_mfma_f32_32x32x16_bf16(A0, B1, zz, 0, 0, 0);
        f32x16 d10 = __builtin_amdgcn_mfma_f32_32x32x16_bf16(A1, B0, zz, 0, 0, 0);
        f32x16 d11 = __builtin_amdgcn_mfma_f32_32x32x16_bf16(A1, B1, zz, 0, 0, 0);
#pragma unroll
        for (int i = 0; i < 16; ++i) {
            m0[i] = fminf(m0[i], fminf(d00[i], d01[i]));
            m1[i] = fminf(m1[i], fminf(d10[i], d11[i]));
        }
    }

    // ---- layout probe: A[m][k] = m (lane&31 broadcast), B[k][n] = 1 ----
    // D[m][n] = 16*m under ANY half<->k assignment, ANY reg->row formula,
    // and ANY lane permutation of rows/cols.
    short8 pa, po;
    unsigned short lv = f2bf((float)col);
#pragma unroll
    for (int i = 0; i < 8; ++i) { pa[i] = (short)lv; po[i] = (short)0x3F80u; }
    f32x16 pr = __builtin_amdgcn_mfma_f32_32x32x16_bf16(pa, po, zz, 0, 0, 0);
    int rowidx[16];
#pragma unroll
    for (int i = 0; i < 16; ++i) rowidx[i] = (int)(pr[i] * 0.0625f + 0.5f);
    const bool row_on_lane = (rowidx[0] == rowidx[1]);   // wave-uniform

    unsigned int* mb = minbuf + (size_t)p * N;
    if (!row_on_lane) {
        // cols on lanes: butterfly min across the 32 lanes of each half
#pragma unroll
        for (int off = 1; off <= 16; off <<= 1) {
#pragma unroll
            for (int i = 0; i < 16; ++i) {
                m0[i] = fminf(m0[i], __shfl_xor(m0[i], off, 64));
                m1[i] = fminf(m1[i], __shfl_xor(m1[i], off, 64));
            }
        }
        if (col == 0) {
#pragma unroll
            for (int r = 0; r < 16; ++r) {
                atomicMin(&mb[abase + rowidx[r]],
                          __float_as_uint(fmaxf(m0[r], 0.0f)));
                atomicMin(&mb[abase + 32 + rowidx[r]],
                          __float_as_uint(fmaxf(m1[r], 0.0f)));
            }
        }
    } else {
        // rows on lanes (row = lane&31): min over regs in-lane, then across halves
        float v0 = m0[0], v1 = m1[0];
#pragma unroll
        for (int i = 1; i < 16; ++i) { v0 = fminf(v0, m0[i]); v1 = fminf(v1, m1[i]); }
        v0 = fminf(v0, __shfl_xor(v0, 32, 64));
        v1 = fminf(v1, __shfl_xor(v1, 32, 64));
        if (half == 0) {
            atomicMin(&mb[abase + col],      __float_as_uint(fmaxf(v0, 0.0f)));
            atomicMin(&mb[abase + 32 + col], __float_as_uint(fmaxf(v1, 0.0f)));
        }
    }
}

// Kernel 3: d = sqrt(min d^2), block-reduce, scaled atomicAdd into scalar out.
__global__ void finalize_kernel(const unsigned int* __restrict__ minbuf,
                                float* __restrict__ out, float scale) {
    __shared__ float red[BLK / 64];
    int idx = blockIdx.x * blockDim.x + threadIdx.x;
    float d = sqrtf(__uint_as_float(minbuf[idx]));
#pragma unroll
    for (int off = 32; off >= 1; off >>= 1)
        d += __shfl_down(d, off, 64);
    int lane = threadIdx.x & 63;
    int wid  = threadIdx.x >> 6;
    if (lane == 0) red[wid] = d;
    __syncthreads();
    if (threadIdx.x == 0) {
        float s = 0.0f;
#pragma unroll
        for (int wv = 0; wv < BLK / 64; ++wv) s += red[wv];
        atomicAdd(out, s * scale);
    }
}

extern "C" void kernel_launch(void* const* d_in, const int* in_sizes, int n_in,
                              void* d_out, int out_size, void* d_ws, size_t ws_size,
                              hipStream_t stream) {
    const float* points = (const float*)d_in[0];   // V x N x 3 fp32
    const float* poses  = (const float*)d_in[1];   // V x 4 x 4 fp32
    float* out = (float*)d_out;                    // scalar fp32

    const int N = in_sizes[0] / (VNUM * 3);        // 8192

    // ws: afr (V*N*16 bf16 = 1MB) | bfr (1MB) | minbuf (6*N uint = 192KB)
    unsigned short* afr = (unsigned short*)d_ws;
    unsigned short* bfr = afr + (size_t)VNUM * N * 16;
    unsigned int* minbuf = (unsigned int*)(bfr + (size_t)VNUM * N * 16);

    int setup_threads = NPAIRS * N;
    setup_kernel<<<(setup_threads + BLK - 1) / BLK, BLK, 0, stream>>>(
        points, poses, afr, bfr, minbuf, out, N);

    dim3 grid(N / 2048, N / 256, NPAIRS);          // 4 x 32 x 6 = 768 blocks
    chamfer_kernel<<<grid, BLK, 0, stream>>>(afr, bfr, minbuf, N);

    finalize_kernel<<<(NPAIRS * N) / BLK, BLK, 0, stream>>>(
        minbuf, out, 1.0f / (6.0f * (float)N));
}

// Round 6
// 32.415 us; speedup vs baseline: 1.4329x; 1.0629x over previous
//
#include <hip/hip_runtime.h>
#include <math.h>

// V=4 views, N=8192 points, 6 directed chamfer terms (pair p rows=view pi, min over view pj)
#define VNUM   4
#define NPAIRS 6
#define BLK    256
#define QTILE  2048   // b-points per block (quarter of N)
#define CHUNK  1024   // b-points staged per LDS phase (32 KB)

using short8  = __attribute__((ext_vector_type(8)))  short;
using f32x16  = __attribute__((ext_vector_type(16))) float;

__device__ inline unsigned short f2bf(float x) {           // RNE to bf16
    unsigned u = __float_as_uint(x);
    return (unsigned short)((u + 0x7FFFu + ((u >> 16) & 1u)) >> 16);
}
__device__ inline float bf2f(unsigned short b) {
    return __uint_as_float(((unsigned)b) << 16);
}

// Kernel 1: world-transform, build K=16 bf16 fragments so that
// dot(Afrag[a], Bfrag[b]) = |a|^2 + |b|^2 - 2*(a_hi+a_lo).(b_hi+b_lo).
__global__ void setup_kernel(const float* __restrict__ pts,
                             const float* __restrict__ poses,
                             unsigned short* __restrict__ afr,
                             unsigned short* __restrict__ bfr,
                             unsigned int* __restrict__ minbuf,
                             float* __restrict__ out, int N) {
    int idx = blockIdx.x * blockDim.x + threadIdx.x;
    if (idx < NPAIRS * N) minbuf[idx] = 0x7F7FFFFFu;       // FLT_MAX bits
    if (idx == 0) *out = 0.0f;
    if (idx < VNUM * N) {
        int v = idx / N;
        const float* P = poses + v * 16;                   // row-major 4x4
        float px = pts[idx*3+0], py = pts[idx*3+1], pz = pts[idx*3+2];
        float x = fmaf(P[0], px, fmaf(P[1], py, fmaf(P[2],  pz, P[3])));
        float y = fmaf(P[4], px, fmaf(P[5], py, fmaf(P[6],  pz, P[7])));
        float z = fmaf(P[8], px, fmaf(P[9], py, fmaf(P[10], pz, P[11])));
        float s = fmaf(x, x, fmaf(y, y, z * z));
        unsigned short xh = f2bf(x), yh = f2bf(y), zh = f2bf(z);
        unsigned short xl = f2bf(x - bf2f(xh));
        unsigned short yl = f2bf(y - bf2f(yh));
        unsigned short zl = f2bf(z - bf2f(zh));
        unsigned short sh = f2bf(s), sl = f2bf(s - bf2f(sh));
        const unsigned short one = 0x3F80u;
        // -2 * bf16 is exact (power-of-two scale)
        unsigned short bxh = f2bf(-2.0f * bf2f(xh)), byh = f2bf(-2.0f * bf2f(yh)),
                       bzh = f2bf(-2.0f * bf2f(zh));
        unsigned short bxl = f2bf(-2.0f * bf2f(xl)), byl = f2bf(-2.0f * bf2f(yl)),
                       bzl = f2bf(-2.0f * bf2f(zl));
        unsigned short* A = afr + (size_t)idx * 16;
        A[0]=xh;  A[1]=yh;  A[2]=zh;   A[3]=xh;  A[4]=yh;  A[5]=zh;
        A[6]=xl;  A[7]=yl;  A[8]=zl;   A[9]=sh;  A[10]=sl; A[11]=one; A[12]=one;
        A[13]=xl; A[14]=yl; A[15]=zl;
        unsigned short* B = bfr + (size_t)idx * 16;
        B[0]=bxh; B[1]=byh; B[2]=bzh;  B[3]=bxl; B[4]=byl; B[5]=bzl;
        B[6]=bxh; B[7]=byh; B[8]=bzh;  B[9]=one; B[10]=one; B[11]=sh; B[12]=sl;
        B[13]=bxl; B[14]=byl; B[15]=bzl;
    }
}

// Kernel 2: wave-task = (pair, 64 a-rows, 2048-b quarter). B-fragments are
// staged to LDS once per 1024-point phase via global_load_lds (width 16),
// with the global source pre-swizzled so LDS = [hi of pts 0..1023][lo of
// pts 0..1023] -> each wave's per-tile ds_read is contiguous 16B/lane
// (2-way bank alias = free). min-accumulate with plain fminf only (NO
// inline asm on MFMA outputs). C/D placement self-calibrated by probe MFMA.
__global__ __launch_bounds__(BLK, 3)
void chamfer_kernel(const unsigned short* __restrict__ afr,
                    const unsigned short* __restrict__ bfr,
                    unsigned int* __restrict__ minbuf, int N) {
    __shared__ short8 sbuf[CHUNK * 2];            // 32 KB: [hi x1024][lo x1024]
    const int p  = blockIdx.z;
    const int pi = (p < 3) ? 0 : ((p < 5) ? 1 : 2);
    const int pj = (p < 3) ? (p + 1) : ((p < 5) ? (p - 1) : 3);
    const int tid  = threadIdx.x;
    const int w    = tid >> 6;
    const int l    = tid & 63;
    const int col  = l & 31;
    const int half = l >> 5;

    const int abase = (blockIdx.y * 4 + w) * 64;  // 64 a-rows per wave
    const int b0    = blockIdx.x * QTILE;         // b-quarter

    const short8* aptr =
        (const short8*)(afr + ((size_t)pi * N + abase + col) * 16 + half * 8);
    const short8 A0 = aptr[0];
    const short8 A1 = aptr[64];                   // +32 points

    const char* gq = (const char*)(bfr + ((size_t)pj * N + b0) * 16);

    f32x16 m0, m1, zz;
#pragma unroll
    for (int i = 0; i < 16; ++i) { m0[i] = 3.402823466e38f; m1[i] = 3.402823466e38f; zz[i] = 0.0f; }

    const short8* bsel = half ? (sbuf + CHUNK) : sbuf;

    for (int c = 0; c < QTILE / CHUNK; ++c) {
        __syncthreads();                          // previous phase fully consumed
        const char* gc = gq + (size_t)c * CHUNK * 32;
#pragma unroll
        for (int it = 0; it < (CHUNK * 32) / (BLK * 16); ++it) {   // 8 iters
            int i = it * BLK + tid;               // 0..2047 linear LDS slot
            const char* src = (i < CHUNK) ? (gc + (size_t)i * 32)
                                          : (gc + (size_t)(i - CHUNK) * 32 + 16);
            __builtin_amdgcn_global_load_lds(
                (const __attribute__((address_space(1))) unsigned int*)src,
                (__attribute__((address_space(3))) unsigned int*)(sbuf + i),
                16, 0, 0);
        }
        __syncthreads();                          // drains vmcnt, data visible

        for (int t = 0; t < CHUNK / 32; t += 2) { // 2 b-tiles per iteration
            short8 B0 = bsel[t * 32 + col];
            short8 B1 = bsel[(t + 1) * 32 + col];
            f32x16 d00 = __builtin_amdgcn_mfma_f32_32x32x16_bf16(A0, B0, zz, 0, 0, 0);
            f32x16 d01 = __builtin_amdgcn_mfma_f32_32x32x16_bf16(A0, B1, zz, 0, 0, 0);
            f32x16 d10 = __builtin_amdgcn_mfma_f32_32x32x16_bf16(A1, B0, zz, 0, 0, 0);
            f32x16 d11 = __builtin_amdgcn_mfma_f32_32x32x16_bf16(A1, B1, zz, 0, 0, 0);
#pragma unroll
            for (int i = 0; i < 16; ++i) {        // fminf only -> v_min3 fusion
                m0[i] = fminf(m0[i], fminf(d00[i], d01[i]));
                m1[i] = fminf(m1[i], fminf(d10[i], d11[i]));
            }
        }
    }

    // ---- layout probe: A[m][k] = m (lane&31 broadcast), B[k][n] = 1 ----
    // D[m][n] = 16*m under ANY half<->k assignment and ANY reg->row formula.
    short8 pa, po;
    unsigned short lv = f2bf((float)col);
#pragma unroll
    for (int i = 0; i < 8; ++i) { pa[i] = (short)lv; po[i] = (short)0x3F80u; }
    f32x16 pr = __builtin_amdgcn_mfma_f32_32x32x16_bf16(pa, po, zz, 0, 0, 0);
    int rowidx[16];
#pragma unroll
    for (int i = 0; i < 16; ++i) rowidx[i] = (int)(pr[i] * 0.0625f + 0.5f);
    const bool row_on_lane = (rowidx[0] == rowidx[1]);   // wave-uniform

    unsigned int* mb = minbuf + (size_t)p * N;
    if (!row_on_lane) {
        // cols on lanes: butterfly min across the 32 lanes of each half
#pragma unroll
        for (int off = 1; off <= 16; off <<= 1) {
#pragma unroll
            for (int i = 0; i < 16; ++i) {
                m0[i] = fminf(m0[i], __shfl_xor(m0[i], off, 64));
                m1[i] = fminf(m1[i], __shfl_xor(m1[i], off, 64));
            }
        }
        if (col == 0) {
#pragma unroll
            for (int r = 0; r < 16; ++r) {
                atomicMin(&mb[abase + rowidx[r]],
                          __float_as_uint(fmaxf(m0[r], 0.0f)));
                atomicMin(&mb[abase + 32 + rowidx[r]],
                          __float_as_uint(fmaxf(m1[r], 0.0f)));
            }
        }
    } else {
        // rows on lanes (row = lane&31): min over regs in-lane, then across halves
        float v0 = m0[0], v1 = m1[0];
#pragma unroll
        for (int i = 1; i < 16; ++i) { v0 = fminf(v0, m0[i]); v1 = fminf(v1, m1[i]); }
        v0 = fminf(v0, __shfl_xor(v0, 32, 64));
        v1 = fminf(v1, __shfl_xor(v1, 32, 64));
        if (half == 0) {
            atomicMin(&mb[abase + col],      __float_as_uint(fmaxf(v0, 0.0f)));
            atomicMin(&mb[abase + 32 + col], __float_as_uint(fmaxf(v1, 0.0f)));
        }
    }
}

// Kernel 3: d = sqrt(min d^2), block-reduce, scaled atomicAdd into scalar out.
__global__ void finalize_kernel(const unsigned int* __restrict__ minbuf,
                                float* __restrict__ out, float scale) {
    __shared__ float red[BLK / 64];
    int idx = blockIdx.x * blockDim.x + threadIdx.x;
    float d = sqrtf(__uint_as_float(minbuf[idx]));
#pragma unroll
    for (int off = 32; off >= 1; off >>= 1)
        d += __shfl_down(d, off, 64);
    int lane = threadIdx.x & 63;
    int wid  = threadIdx.x >> 6;
    if (lane == 0) red[wid] = d;
    __syncthreads();
    if (threadIdx.x == 0) {
        float s = 0.0f;
#pragma unroll
        for (int wv = 0; wv < BLK / 64; ++wv) s += red[wv];
        atomicAdd(out, s * scale);
    }
}

extern "C" void kernel_launch(void* const* d_in, const int* in_sizes, int n_in,
                              void* d_out, int out_size, void* d_ws, size_t ws_size,
                              hipStream_t stream) {
    const float* points = (const float*)d_in[0];   // V x N x 3 fp32
    const float* poses  = (const float*)d_in[1];   // V x 4 x 4 fp32
    float* out = (float*)d_out;                    // scalar fp32

    const int N = in_sizes[0] / (VNUM * 3);        // 8192

    // ws: afr (V*N*16 bf16 = 1MB) | bfr (1MB) | minbuf (6*N uint = 192KB)
    unsigned short* afr = (unsigned short*)d_ws;
    unsigned short* bfr = afr + (size_t)VNUM * N * 16;
    unsigned int* minbuf = (unsigned int*)(bfr + (size_t)VNUM * N * 16);

    int setup_threads = NPAIRS * N;
    setup_kernel<<<(setup_threads + BLK - 1) / BLK, BLK, 0, stream>>>(
        points, poses, afr, bfr, minbuf, out, N);

    dim3 grid(N / QTILE, N / 256, NPAIRS);         // 4 x 32 x 6 = 768 blocks
    chamfer_kernel<<<grid, BLK, 0, stream>>>(afr, bfr, minbuf, N);

    finalize_kernel<<<(NPAIRS * N) / BLK, BLK, 0, stream>>>(
        minbuf, out, 1.0f / (6.0f * (float)N));
}